// Round 6
// baseline (215.844 us; speedup 1.0000x reference)
//
#include <hip/hip_runtime.h>

// TsSub: out[b, p, t] = x[b, I[p], t*10] - x[b, J[p], t*10]
// x: (256, 64, 2000) f32, out: (256, 2016, 200) f32, (I,J)=triu_indices(64,k=1)
//
// Single fused kernel, T-split: block = (b, q) with q = time-half.
// Sampled t in [100q, 100q+100) lives in floats [1000q, 1000q+1000) of each
// x-row -> contiguous, float4-aligned, read by exactly ONE block (no
// amplification, no ws round-trip). Stage extracted samples in LDS, emit all
// 2016 pair half-rows as 16B vectors.

#define NB     256
#define NF     64
#define RF4    500    // vec4 per x row (2000 floats)
#define HF4    250    // vec4 per half row
#define SPAD   104    // floats per LDS row (= 26 vec4)
#define NPAIR  2016
#define TV4H   25     // vec4 per out half-row
#define OF4    50     // vec4 per out full row

typedef float fx4 __attribute__((ext_vector_type(4)));

__global__ __launch_bounds__(256)
void ts_sub_fused(const fx4* __restrict__ xv, fx4* __restrict__ out) {
    __shared__ __attribute__((aligned(16))) float sf[NF * SPAD];  // 26.6 KB
    __shared__ unsigned char pi[NPAIR];
    __shared__ unsigned char pj[NPAIR];

    const int tid = threadIdx.x;
    const int b = blockIdx.x >> 1;
    const int q = blockIdx.x & 1;
    const fx4* __restrict__ xb = xv + (size_t)b * (NF * RF4) + q * HF4;

    // --- pair table (8 iters/thread) ---
    for (int p = tid; p < NPAIR; p += 256) {
        float d = 16129.0f - 8.0f * (float)p;          // 127^2 - 8p
        int i = (int)((127.0f - sqrtf(d)) * 0.5f);
        if (i < 0) i = 0;
        while (i > 0 && (i * (127 - i)) / 2 > p) --i;
        while (((i + 1) * (126 - i)) / 2 <= p) ++i;
        pi[p] = (unsigned char)i;
        pj[p] = (unsigned char)(p - (i * (127 - i)) / 2 + i + 1);
    }

    // --- stage: coalesced read of 64 half-rows, extract every 10th float ---
    // vec4 index m within half-row: m%5==0 -> .x is sample 2*(m/5),
    //                               m%5==2 -> .z is sample 2*(m/5)+1
    {
        int idx = tid;
        int row = idx / HF4;
        int m   = idx - row * HF4;
        while (idx < NF * HF4) {               // 16000 vec4
            fx4 v = __builtin_nontemporal_load(&xb[row * RF4 + m]);
            int a = m / 5;
            int r = m - a * 5;
            if (r == 0)      sf[row * SPAD + 2 * a]     = v.x;
            else if (r == 2) sf[row * SPAD + 2 * a + 1] = v.z;
            idx += 256;                        // 256 = 250 + 6
            row += 1;
            m += 6;
            if (m >= HF4) { m -= HF4; ++row; }
        }
    }
    __syncthreads();

    // --- emit: 2016 pair half-rows x 25 vec4, streaming nt stores ---
    const fx4* __restrict__ s4 = reinterpret_cast<const fx4*>(sf); // row stride 26
    fx4* __restrict__ ob = out + (size_t)b * (NPAIR * OF4) + q * TV4H;

    int v  = tid;
    int p  = v / TV4H;
    int t4 = v - p * TV4H;
    while (v < NPAIR * TV4H) {                 // 50400 vec4
        fx4 a = s4[pi[p] * 26 + t4];
        fx4 c = s4[pj[p] * 26 + t4];
        fx4 r = a - c;
        __builtin_nontemporal_store(r, &ob[(size_t)p * OF4 + t4]);
        v += 256;                              // 256 = 10*25 + 6
        p += 10;
        t4 += 6;
        if (t4 >= TV4H) { t4 -= TV4H; ++p; }
    }
}

extern "C" void kernel_launch(void* const* d_in, const int* in_sizes, int n_in,
                              void* d_out, int out_size, void* d_ws, size_t ws_size,
                              hipStream_t stream) {
    const float* x = (const float*)d_in[0];
    float* out = (float*)d_out;
    ts_sub_fused<<<dim3(NB * 2), dim3(256), 0, stream>>>(
        (const fx4*)x, (fx4*)out);
}

// Round 7
// 186.898 us; speedup vs baseline: 1.1549x; 1.1549x over previous
//
#include <hip/hip_runtime.h>

// TsSub: out[b, p, t] = x[b, I[p], t*10] - x[b, J[p], t*10]
// x: (256, 64, 2000) f32, out: (256, 2016, 200) f32, (I,J)=triu_indices(64,k=1)
//
// Single fused kernel, T-split: block = (b, q), q = time-half, 1024 threads.
// Sampled t in [100q,100q+100) lives in floats [1000q,1000q+1000) of each
// x-row: contiguous, vec4-aligned, read by exactly ONE block. Stage loads
// only vec4s holding samples (m = 5u or 5u+2 -> .x/.z), which still covers
// every 64B line once. Emit all 2016 pair half-rows as 16B nt stores.

#define NB     256
#define NF     64
#define RF4    500    // vec4 per x row (2000 floats)
#define HF4    250    // vec4 per half row
#define SPAD   104    // floats per LDS row (= 26 vec4)
#define NPAIR  2016
#define TV4H   25     // vec4 per out half-row
#define OF4    50     // vec4 per out full row
#define NT     1024   // threads per block

typedef float fx4 __attribute__((ext_vector_type(4)));

__global__ __launch_bounds__(NT)
void ts_sub_fused(const fx4* __restrict__ xv, fx4* __restrict__ out) {
    __shared__ __attribute__((aligned(16))) float sf[NF * SPAD];  // 26.6 KB
    __shared__ unsigned char pi[NPAIR];
    __shared__ unsigned char pj[NPAIR];

    const int tid = threadIdx.x;
    const int b = blockIdx.x >> 1;
    const int q = blockIdx.x & 1;
    const fx4* __restrict__ xb = xv + (size_t)b * (NF * RF4) + q * HF4;

    // --- pair table (2 iters/thread) ---
    for (int p = tid; p < NPAIR; p += NT) {
        float d = 16129.0f - 8.0f * (float)p;          // 127^2 - 8p
        int i = (int)((127.0f - sqrtf(d)) * 0.5f);
        if (i < 0) i = 0;
        while (i > 0 && (i * (127 - i)) / 2 > p) --i;
        while (((i + 1) * (126 - i)) / 2 <= p) ++i;
        pi[p] = (unsigned char)i;
        pj[p] = (unsigned char)(p - (i * (127 - i)) / 2 + i + 1);
    }

    // --- stage: load only sample-bearing vec4s of 64 half-rows ---
    // k in [0,100): u=k>>1, par=k&1, m=5u+2par; sample s=k = (par? .z : .x)
    {
        int idx = tid;                    // [0, 6400)
        int row = idx / 100;
        int k   = idx - row * 100;
        while (idx < NF * 100) {
            int u = k >> 1, par = k & 1;
            fx4 v = xb[row * RF4 + 5 * u + 2 * par];
            sf[row * SPAD + k] = par ? v.z : v.x;
            idx += NT;                    // NT = 10*100 + 24
            row += 10;
            k += 24;
            if (k >= 100) { k -= 100; ++row; }
        }
    }
    __syncthreads();

    // --- emit: 2016 pair half-rows x 25 vec4, streaming nt stores ---
    const fx4* __restrict__ s4 = reinterpret_cast<const fx4*>(sf); // row stride 26
    fx4* __restrict__ ob = out + (size_t)b * (NPAIR * OF4) + q * TV4H;

    int v  = tid;
    int p  = v / TV4H;
    int t4 = v - p * TV4H;
    while (v < NPAIR * TV4H) {                 // 50400 vec4
        fx4 a = s4[pi[p] * 26 + t4];
        fx4 c = s4[pj[p] * 26 + t4];
        fx4 r = a - c;
        __builtin_nontemporal_store(r, &ob[(size_t)p * OF4 + t4]);
        v += NT;                               // NT = 40*25 + 24
        p += 40;
        t4 += 24;
        if (t4 >= TV4H) { t4 -= TV4H; ++p; }
    }
}

extern "C" void kernel_launch(void* const* d_in, const int* in_sizes, int n_in,
                              void* d_out, int out_size, void* d_ws, size_t ws_size,
                              hipStream_t stream) {
    const float* x = (const float*)d_in[0];
    float* out = (float*)d_out;
    ts_sub_fused<<<dim3(NB * 2), dim3(NT), 0, stream>>>(
        (const fx4*)x, (fx4*)out);
}

// Round 8
// 110.238 us; speedup vs baseline: 1.9580x; 1.6954x over previous
//
#include <hip/hip_runtime.h>

// TsSub: out[b, p, t] = x[b, I[p], t*10] - x[b, J[p], t*10]
// x: (256, 64, 2000) f32, out: (256, 2016, 200) f32, (I,J)=triu_indices(64,k=1)
//
// Single fused kernel, combo-split: block = (b, group-combo), G=16.
// Stage 32 (16 diag) sampled rows DIRECTLY from x: load only sample-bearing
// vec4s (m = 5u or 5u+2 -> .x/.z), touching every 64B line once. Same-b
// combos made XCD-adjacent so the 4x logical x re-read is L2-served.
// Emit full 800B pair rows (16 consecutive rows = 12.8KB runs), nt stores.

#define NF      64
#define T_OUT   200
#define NPAIR   2016
#define NB      256
#define RF4     500             // vec4 per x row
#define TV4     50              // vec4 per out row
#define SPADF   208             // floats per LDS row (52 vec4)
#define NCOMBO  10
#define NWG     (NB * NCOMBO)   // 2560

typedef float fx4 __attribute__((ext_vector_type(4)));

__constant__ unsigned char kGi[NCOMBO] = {0,1,2,3, 0,0,0,1,1,2};
__constant__ unsigned char kGj[NCOMBO] = {0,1,2,3, 1,2,3,2,3,3};

__global__ __launch_bounds__(256)
void ts_sub_combo(const fx4* __restrict__ xv, fx4* __restrict__ out) {
    __shared__ __attribute__((aligned(16))) float sf[32 * SPADF];  // 26 KB
    __shared__ int obase[256];
    __shared__ unsigned char ir[256];
    __shared__ unsigned char jr[256];

    const int tid = threadIdx.x;
    // bijective XCD-chunk swizzle (2560 % 8 == 0): same-b combos contiguous
    const int n   = blockIdx.x;
    const int blk = (n & 7) * (NWG / 8) + (n >> 3);
    const int b     = blk / NCOMBO;
    const int combo = blk - b * NCOMBO;
    const int gi    = kGi[combo];
    const int gj    = kGj[combo];
    const bool diag = combo < 4;
    const int nrows  = diag ? 16 : 32;
    const int npairs = diag ? 120 : 256;

    // --- pair tables ---
    if (tid < npairs) {
        int il, jl;
        if (diag) {
            il = 0;                                   // base16(i) = i*(31-i)/2
            while ((il + 1) * (30 - il) / 2 <= tid) ++il;
            jl = tid - il * (31 - il) / 2 + il + 1;
            ir[tid] = (unsigned char)il;
            jr[tid] = (unsigned char)jl;
        } else {
            il = tid >> 4; jl = tid & 15;
            ir[tid] = (unsigned char)il;
            jr[tid] = (unsigned char)(16 + jl);
        }
        int i = gi * 16 + il;
        int j = (diag ? gi : gj) * 16 + jl;
        obase[tid] = i * (127 - i) / 2 + (j - i - 1);
    }

    // --- stage sampled rows directly from x ---
    // k in [0,200): u=k>>1, par=k&1, m=5u+2par, sample = par ? .z : .x
    {
        const fx4* __restrict__ xb = xv + (size_t)b * (NF * RF4);
        int idx = tid;                    // [0, nrows*200)
        int slot = 0;
        int k = tid;
        if (k >= T_OUT) { slot = 1; k -= T_OUT; }     // tid < 256 < 400
        const int total = nrows * T_OUT;
        while (idx < total) {
            int f = (slot < 16) ? (gi * 16 + slot) : (gj * 16 + slot - 16);
            int u = k >> 1, par = k & 1;
            fx4 v = xb[f * RF4 + 5 * u + 2 * par];
            sf[slot * SPADF + k] = par ? v.z : v.x;
            idx += 256;                   // 256 = 1*200 + 56
            slot += 1;
            k += 56;
            if (k >= T_OUT) { k -= T_OUT; ++slot; }
        }
    }
    __syncthreads();

    // --- emit pair rows: incremental (slot,t4), step 256 = 5*50 + 6 ---
    const fx4* __restrict__ s4 = reinterpret_cast<const fx4*>(sf); // row stride 52
    fx4* __restrict__ ob = out + (size_t)b * (NPAIR * TV4);
    const int total = npairs * TV4;          // 12800 or 6000
    int v    = tid;
    int slot = v / TV4;
    int t4   = v - slot * TV4;
    while (v < total) {
        fx4 a = s4[ir[slot] * 52 + t4];
        fx4 c = s4[jr[slot] * 52 + t4];
        fx4 r = a - c;
        __builtin_nontemporal_store(r, &ob[(size_t)obase[slot] * TV4 + t4]);
        v += 256;
        slot += 5;
        t4 += 6;
        if (t4 >= TV4) { t4 -= TV4; ++slot; }
    }
}

extern "C" void kernel_launch(void* const* d_in, const int* in_sizes, int n_in,
                              void* d_out, int out_size, void* d_ws, size_t ws_size,
                              hipStream_t stream) {
    const float* x = (const float*)d_in[0];
    float* out = (float*)d_out;
    ts_sub_combo<<<dim3(NWG), dim3(256), 0, stream>>>(
        (const fx4*)x, (fx4*)out);
}